// Round 4
// baseline (619.099 us; speedup 1.0000x reference)
//
#include <hip/hip_runtime.h>

#define NWIN 1024
#define LTOK 256
#define EMB  192
#define NPAT 64
#define NHEAD 6
#define HDIM 32
#define SCALE 0.08838834764831845f
#define LN_EPS 1e-5f

typedef float f32x4 __attribute__((ext_vector_type(4)));
typedef short s16x8 __attribute__((ext_vector_type(8)));

// ---- attention kernel LDS layout (bytes) ----
#define OFF_KH  0        // [64 p][128 sc] bf16, row 256B, swz ((p&7)<<4)
#define OFF_VT  16384    // [128 sc][64 k] bf16, row 128B, swz ((sc&7)<<4)
#define OFF_PB  32768    // [64 q][64 k]  bf16, row 128B, swz ((q&7)<<4)
#define OFF_OB  40960    // [64 qp][2 hp][128 sc] bf16, row 512B, swz ((qp>>2)&3)<<5 ; phase1 partials
#define OFF_ST  73728    // stats: 6 x 64 f32
#define OFF_BH  75264    // bias_h: 225 f32 (pad 1024)
#define OFF_HB  76288    // halfbuf: [64 qr][2 half] float2 (m,s) = 1024B
#define SMEM_BYTES 77312 // -> 2 blocks/CU

__device__ __forceinline__ unsigned short f2bf(float f) {
    unsigned u = __float_as_uint(f);
    u += 0x7fffu + ((u >> 16) & 1u);
    return (unsigned short)(u >> 16);
}

__device__ __forceinline__ int tok_of(int p, int s) {
    // t = wh*32 + sh*16 + ww*2 + sw ; p = wh*8+ww, s = sh*2+sw
    return ((p >> 3) << 5) + ((s >> 1) << 4) + ((p & 7) << 1) + (s & 1);
}

__device__ __forceinline__ f32x4 mfma16(s16x8 a, s16x8 b, f32x4 c) {
    return __builtin_amdgcn_mfma_f32_16x16x32_bf16(a, b, c, 0, 0, 0);
}

__device__ __forceinline__ s16x8 ln_pack8r(const float* v, float mu, float rs,
                                           const float* __restrict__ wl,
                                           const float* __restrict__ bl,
                                           float scale) {
    f32x4 w0 = *(const f32x4*)wl;
    f32x4 w1 = *(const f32x4*)(wl + 4);
    f32x4 c0 = *(const f32x4*)bl;
    f32x4 c1 = *(const f32x4*)(bl + 4);
    s16x8 r;
    r[0] = (short)f2bf(((v[0]-mu)*rs*w0[0] + c0[0])*scale);
    r[1] = (short)f2bf(((v[1]-mu)*rs*w0[1] + c0[1])*scale);
    r[2] = (short)f2bf(((v[2]-mu)*rs*w0[2] + c0[2])*scale);
    r[3] = (short)f2bf(((v[3]-mu)*rs*w0[3] + c0[3])*scale);
    r[4] = (short)f2bf(((v[4]-mu)*rs*w1[0] + c1[0])*scale);
    r[5] = (short)f2bf(((v[5]-mu)*rs*w1[1] + c1[1])*scale);
    r[6] = (short)f2bf(((v[6]-mu)*rs*w1[2] + c1[2])*scale);
    r[7] = (short)f2bf(((v[7]-mu)*rs*w1[3] + c1[3])*scale);
    return r;
}

__device__ __forceinline__ void ln_f8r(const float* v, float mu, float rs,
                                       const float* __restrict__ wl,
                                       const float* __restrict__ bl,
                                       float* o) {
    f32x4 w0 = *(const f32x4*)wl;
    f32x4 w1 = *(const f32x4*)(wl + 4);
    f32x4 c0 = *(const f32x4*)bl;
    f32x4 c1 = *(const f32x4*)(bl + 4);
    o[0] = (v[0]-mu)*rs*w0[0] + c0[0];
    o[1] = (v[1]-mu)*rs*w0[1] + c0[1];
    o[2] = (v[2]-mu)*rs*w0[2] + c0[2];
    o[3] = (v[3]-mu)*rs*w0[3] + c0[3];
    o[4] = (v[4]-mu)*rs*w1[0] + c1[0];
    o[5] = (v[5]-mu)*rs*w1[1] + c1[1];
    o[6] = (v[6]-mu)*rs*w1[2] + c1[2];
    o[7] = (v[7]-mu)*rs*w1[3] + c1[3];
}

// mapping: p = tid&63 (lane-distinct -> conflict-free LDS), scb = (tid>>6)*2+i
__device__ __forceinline__ void load_T8(const float* __restrict__ g, size_t wbase,
                                        int tid, int hh, float pre[2][8]) {
    int p = tid & 63;
    #pragma unroll
    for (int i = 0; i < 2; ++i) {
        int scb = (tid >> 6) * 2 + i;
        int s = scb >> 2, cbx = scb & 3;
        int t = tok_of(p, s);
        const float* gp = g + wbase + t*EMB + hh*HDIM + cbx*8;
        *(f32x4*)&pre[i][0] = *(const f32x4*)gp;
        *(f32x4*)&pre[i][4] = *(const f32x4*)(gp + 4);
    }
}

__device__ __forceinline__ void stage_K(char* smem, int tid, int hh,
                                        const float kpre[2][8], const float* stats,
                                        const float* __restrict__ lnkw,
                                        const float* __restrict__ lnkb) {
    const float* muk = stats + 128; const float* rsk = stats + 192;
    int p = tid & 63;
    #pragma unroll
    for (int i = 0; i < 2; ++i) {
        int scb = (tid >> 6) * 2 + i;
        int s = scb >> 2, cbx = scb & 3;
        int chb = hh*HDIM + cbx*8;
        s16x8 kk = ln_pack8r(kpre[i], muk[p], rsk[p],
                             lnkw + s*EMB + chb, lnkb + s*EMB + chb, 1.0f);
        *(s16x8*)(smem + OFF_KH + p*256 + ((scb*16) ^ ((p & 7) << 4))) = kk;
    }
}

__device__ __forceinline__ void stage_V(char* smem, int tid, int hh,
                                        const float vpre[2][8], const float* stats,
                                        const float* __restrict__ lnvw,
                                        const float* __restrict__ lnvb) {
    const float* muv = stats + 256; const float* rsv = stats + 320;
    int p = tid & 63;
    #pragma unroll
    for (int i = 0; i < 2; ++i) {
        int scb = (tid >> 6) * 2 + i;
        int s = scb >> 2, cbx = scb & 3;
        int chb = hh*HDIM + cbx*8;
        float vn[8];
        ln_f8r(vpre[i], muv[p], rsv[p], lnvw + s*EMB + chb, lnvb + s*EMB + chb, vn);
        #pragma unroll
        for (int j = 0; j < 8; ++j) {
            int sc = scb*8 + j;   // = s*32 + cbx*8 + j
            // 64 lanes: same row sc, cols p*2 -> 2 lanes/bank = free
            *(unsigned short*)(smem + OFF_VT + sc*128 + ((p*2) ^ ((sc & 7) << 4)))
                = f2bf(vn[j]);
        }
    }
}

__device__ __forceinline__ void load_Q(const float* __restrict__ q_g, size_t wbase,
                                       int pr, int cb, int hh, float qpre[4][8]) {
    #pragma unroll
    for (int ks = 0; ks < 4; ++ks) {
        int t = tok_of(pr, ks);
        const float* qp = q_g + wbase + t*EMB + hh*HDIM + cb*8;
        *(f32x4*)&qpre[ks][0] = *(const f32x4*)qp;
        *(f32x4*)&qpre[ks][4] = *(const f32x4*)(qp + 4);
    }
}

// Pre-projection bf16 rows live INSIDE d_out: window w, token t occupies
// bytes [w*196608 + t*768 + 384, +384). Stored as full 128B lines (head pairs).

__global__ __launch_bounds__(512, 4) void dwa_attn_kernel(
    const float* __restrict__ q_g, const float* __restrict__ k_g,
    const float* __restrict__ v_g, const float* __restrict__ mask_g,
    const float* __restrict__ lnqw, const float* __restrict__ lnqb,
    const float* __restrict__ lnkw, const float* __restrict__ lnkb,
    const float* __restrict__ lnvw, const float* __restrict__ lnvb,
    const float* __restrict__ btab, float* __restrict__ out_g)
{
    __shared__ __align__(16) char smem[SMEM_BYTES];

    const int tid  = threadIdx.x;
    const int lane = tid & 63;
    const int wv   = tid >> 6;
    const int win  = blockIdx.x;
    const size_t wbase = (size_t)win * LTOK * EMB;
    char* preb = (char*)out_g + (size_t)win * 196608;

    float* stats = (float*)(smem + OFF_ST);
    float* muq = stats;       float* rsq = stats + 64;
    float* biash = (float*)(smem + OFF_BH);
    float2* HB = (float2*)(smem + OFF_HB);

    const int mstrip = wv >> 1, nhalf = wv & 1;
    const int l15 = lane & 15, l4 = lane >> 4;
    const int pr = mstrip*16 + l15;
    const int cb = l4;

    // ---- per-lane mask regs + bias gather indices (QK^T D-reg mapping) ----
    const float* mask_w = mask_g + (size_t)(win & 63) * NPAT * NPAT;
    const int kc0 = nhalf*32 + l15, kc1 = kc0 + 16;
    float mm0[4], mm1[4];
    int idx0[4], idx1[4], qrr[4];
    {
        int kh0 = kc0 >> 3, kw0 = kc0 & 7, kh1 = kc1 >> 3, kw1 = kc1 & 7;
        #pragma unroll
        for (int r = 0; r < 4; ++r) {
            int qr = mstrip*16 + l4*4 + r;
            qrr[r] = qr;
            mm0[r] = mask_w[qr*64 + kc0];
            mm1[r] = mask_w[qr*64 + kc1];
            idx0[r] = ((qr>>3) - kh0 + 7)*15 + ((qr&7) - kw0 + 7);
            idx1[r] = ((qr>>3) - kh1 + 7)*15 + ((qr&7) - kw1 + 7);
        }
    }

    // ---------------- Phase 1: LN stats for q,k,v (single pass) ----------------
    {
        float* part = (float*)(smem + OFF_OB);   // [256 t][2 half][6]
        const int t = tid >> 1, half = tid & 1;
        const f32x4* qp = (const f32x4*)(q_g + wbase + t*EMB + half*96);
        const f32x4* kp = (const f32x4*)(k_g + wbase + t*EMB + half*96);
        const f32x4* vp = (const f32x4*)(v_g + wbase + t*EMB + half*96);
        float s1q=0.f,s2q=0.f,s1k=0.f,s2k=0.f,s1v=0.f,s2v=0.f;
        #pragma unroll 4
        for (int i = 0; i < 24; ++i) {
            f32x4 a = qp[i];
            s1q += a[0]+a[1]+a[2]+a[3];
            s2q += a[0]*a[0]+a[1]*a[1]+a[2]*a[2]+a[3]*a[3];
            f32x4 b = kp[i];
            s1k += b[0]+b[1]+b[2]+b[3];
            s2k += b[0]*b[0]+b[1]*b[1]+b[2]*b[2]+b[3]*b[3];
            f32x4 c = vp[i];
            s1v += c[0]+c[1]+c[2]+c[3];
            s2v += c[0]*c[0]+c[1]*c[1]+c[2]*c[2]+c[3]*c[3];
        }
        float* pp = part + (t*2 + half)*6;
        pp[0]=s1q; pp[1]=s2q; pp[2]=s1k; pp[3]=s2k; pp[4]=s1v; pp[5]=s2v;
        __syncthreads();
        if (tid < NPAT) {
            float S[6] = {0.f,0.f,0.f,0.f,0.f,0.f};
            #pragma unroll
            for (int s = 0; s < 4; ++s) {
                int tt = tok_of(tid, s);
                const float* pr_ = part + tt*12;
                #pragma unroll
                for (int x = 0; x < 6; ++x) S[x] += pr_[x] + pr_[6 + x];
            }
            #pragma unroll
            for (int x = 0; x < 3; ++x) {
                float mu  = S[2*x] * (1.f/768.f);
                float var = S[2*x+1] * (1.f/768.f) - mu*mu;
                stats[x*128 + tid]      = mu;
                stats[x*128 + 64 + tid] = rsqrtf(var + LN_EPS);
            }
        }
        __syncthreads();
    }

    // ---------------- Prologue: stage K/V/bias/Q for head 0 ----------------
    float kpre[2][8], vpre[2][8], qpre[4][8];
    float breg;
    load_T8(k_g, wbase, tid, 0, kpre);
    load_T8(v_g, wbase, tid, 0, vpre);
    load_Q(q_g, wbase, pr, cb, 0, qpre);
    breg = (tid < 225) ? btab[tid * NHEAD] : 0.f;
    stage_K(smem, tid, 0, kpre, stats, lnkw, lnkb);
    stage_V(smem, tid, 0, vpre, stats, lnvw, lnvb);
    if (tid < 225) biash[tid] = breg;
    __syncthreads();

    // ---------------- Head loop: 3 barriers per head ----------------
    for (int h = 0; h < NHEAD; ++h) {
        const bool pf = (h < NHEAD-1);
        // step1: issue K/V/bias prefetch for h+1
        if (pf) {
            load_T8(k_g, wbase, tid, h+1, kpre);
            load_T8(v_g, wbase, tid, h+1, vpre);
            breg = (tid < 225) ? btab[tid*NHEAD + h + 1] : 0.f;
        }

        // step2: QK^T + in-register softmax half-reduce
        float e0[4], e1[4], mrow[4], srow[4];
        {
            float mu = muq[pr], rs = rsq[pr];
            f32x4 acc0 = {0.f,0.f,0.f,0.f};
            f32x4 acc1 = {0.f,0.f,0.f,0.f};
            __builtin_amdgcn_s_setprio(1);
            #pragma unroll
            for (int ks = 0; ks < 4; ++ks) {
                int chb = h*HDIM + cb*8;
                s16x8 af = ln_pack8r(qpre[ks], mu, rs,
                                     lnqw + ks*EMB + chb, lnqb + ks*EMB + chb, SCALE);
                {
                    int row = nhalf*32 + l15;
                    s16x8 bf = *(const s16x8*)(smem + OFF_KH + row*256 +
                                  ((ks*64 + cb*16) ^ ((row & 7) << 4)));
                    acc0 = mfma16(af, bf, acc0);
                }
                {
                    int row = nhalf*32 + 16 + l15;
                    s16x8 bf = *(const s16x8*)(smem + OFF_KH + row*256 +
                                  ((ks*64 + cb*16) ^ ((row & 7) << 4)));
                    acc1 = mfma16(af, bf, acc1);
                }
            }
            __builtin_amdgcn_s_setprio(0);
            #pragma unroll
            for (int r = 0; r < 4; ++r) {
                float L0 = acc0[r] + mm0[r] + biash[idx0[r]];
                float L1 = acc1[r] + mm1[r] + biash[idx1[r]];
                float m = fmaxf(L0, L1);
                m = fmaxf(m, __shfl_xor(m, 1));
                m = fmaxf(m, __shfl_xor(m, 2));
                m = fmaxf(m, __shfl_xor(m, 4));
                m = fmaxf(m, __shfl_xor(m, 8));
                float a = __expf(L0 - m), b = __expf(L1 - m);
                float s = a + b;
                s += __shfl_xor(s, 1);
                s += __shfl_xor(s, 2);
                s += __shfl_xor(s, 4);
                s += __shfl_xor(s, 8);
                e0[r] = a; e1[r] = b; mrow[r] = m; srow[r] = s;
            }
            if (l15 == 0) {
                #pragma unroll
                for (int r = 0; r < 4; ++r) {
                    float2 v; v.x = mrow[r]; v.y = srow[r];
                    HB[qrr[r]*2 + nhalf] = v;
                }
            }
        }
        __syncthreads();   // A: halves ready; KH reads done; bias reads done

        // step3: restage KH/bias/Q for h+1; finalize P -> PB
        if (pf) {
            stage_K(smem, tid, h+1, kpre, stats, lnkw, lnkb);
            load_Q(q_g, wbase, pr, cb, h+1, qpre);
            if (tid < 225) biash[tid] = breg;
        }
        #pragma unroll
        for (int r = 0; r < 4; ++r) {
            int qr = qrr[r];
            float2 ha = HB[qr*2 + 0], hb = HB[qr*2 + 1];
            float M = fmaxf(ha.x, hb.x);
            float tot = ha.y*__expf(ha.x - M) + hb.y*__expf(hb.x - M);
            float f = __expf(mrow[r] - M) / tot;
            unsigned short p0 = f2bf(e0[r]*f);
            unsigned short p1 = f2bf(e1[r]*f);
            *(unsigned short*)(smem + OFF_PB + qr*128 + ((kc0*2) ^ ((qr & 7) << 4))) = p0;
            *(unsigned short*)(smem + OFF_PB + qr*128 + ((kc1*2) ^ ((qr & 7) << 4))) = p1;
        }
        __syncthreads();   // B: PB ready; KH(h+1)/bias(h+1) staged

        // step5: P @ V -> OB[h&1]
        {
            s16x8 ap0 = *(const s16x8*)(smem + OFF_PB + pr*128 +
                          ((cb*16) ^ ((pr & 7) << 4)));
            s16x8 ap1 = *(const s16x8*)(smem + OFF_PB + pr*128 +
                          ((64 + cb*16) ^ ((pr & 7) << 4)));
            __builtin_amdgcn_s_setprio(1);
            #pragma unroll
            for (int i = 0; i < 4; ++i) {
                int nt = nhalf*4 + i;
                int brow = nt*16 + l15;     // sc
                f32x4 acc = {0.f,0.f,0.f,0.f};
                s16x8 bf0 = *(const s16x8*)(smem + OFF_VT + brow*128 +
                              ((cb*16) ^ ((brow & 7) << 4)));
                s16x8 bf1 = *(const s16x8*)(smem + OFF_VT + brow*128 +
                              ((64 + cb*16) ^ ((brow & 7) << 4)));
                acc = mfma16(ap0, bf0, acc);
                acc = mfma16(ap1, bf1, acc);
                int sc = nt*16 + l15;
                #pragma unroll
                for (int r = 0; r < 4; ++r) {
                    int qp = mstrip*16 + l4*4 + r;
                    *(unsigned short*)(smem + OFF_OB + qp*512 +
                        (((h & 1)*256 + sc*2) ^ (((qp >> 2) & 3) << 5))) = f2bf(acc[r]);
                }
            }
            __builtin_amdgcn_s_setprio(0);
        }
        __syncthreads();   // C: OB ready; VT reads done

        // step6: every 2nd head, store full 128B/token head-pair lines
        if (h & 1) {
            int hpair = h >> 1;
            #pragma unroll
            for (int i = 0; i < 4; ++i) {
                int c = i*512 + tid;             // 2048 chunks of 16B
                int t = c >> 3, ch8 = c & 7;
                int hp = ch8 >> 2, c2b = ch8 & 3;
                int qp = ((t >> 5) << 3) | ((t >> 1) & 7);
                int s  = (((t >> 4) & 1) << 1) | (t & 1);
                s16x8 v = *(const s16x8*)(smem + OFF_OB + qp*512 +
                              ((hp*256 + s*64 + c2b*16) ^ (((qp >> 2) & 3) << 5)));
                *(s16x8*)(preb + (size_t)t*768 + 384 + hpair*128 + hp*64 + c2b*16) = v;
            }
        }
        // step7: restage VT for h+1 (reads done at C; next read after h+1's B)
        if (pf) stage_V(smem, tid, h+1, vpre, stats, lnvw, lnvb);
        // no barrier here: VT/PB/KH/bias next touched only after h+1's A/B
    }
}

// ---- projection: 1 block per window, W staged bf16 in LDS once ----
__global__ __launch_bounds__(256, 2) void dwa_proj_kernel(
    const float* __restrict__ pw, float* __restrict__ out_g)
{
    __shared__ __align__(16) char smem[73728];   // [192 orow][192 ch] bf16, swz

    const int tid  = threadIdx.x;
    const int lane = tid & 63;
    const int wv   = tid >> 6;
    const int w    = blockIdx.x;
    const char* preb = (const char*)out_g + (size_t)w * 196608;
    const int cb = lane >> 4;

    // preload all A fragments (issued before staging; overlaps W stage + barrier)
    s16x8 af[4][6];
    #pragma unroll
    for (int si = 0; si < 4; ++si) {
        int strip = wv*4 + si;
        int arow = strip*16 + (lane & 15);
        #pragma unroll
        for (int ks = 0; ks < 6; ++ks)
            af[si][ks] = *(const s16x8*)(preb + (size_t)arow*768 + 384 + ks*64 + cb*16);
    }

    // stage W (192x192 f32 -> bf16), 4608 chunks of 8
    #pragma unroll 2
    for (int i = 0; i < 18; ++i) {
        int c = i*256 + tid;
        int orow = c / 24, cb8 = c % 24;
        const float* wp = pw + (size_t)orow*EMB + cb8*8;
        f32x4 a = *(const f32x4*)wp;
        f32x4 b = *(const f32x4*)(wp + 4);
        s16x8 w8;
        w8[0] = (short)f2bf(a[0]); w8[1] = (short)f2bf(a[1]);
        w8[2] = (short)f2bf(a[2]); w8[3] = (short)f2bf(a[3]);
        w8[4] = (short)f2bf(b[0]); w8[5] = (short)f2bf(b[1]);
        w8[6] = (short)f2bf(b[2]); w8[7] = (short)f2bf(b[3]);
        *(s16x8*)(smem + orow*384 + ((cb8*16) ^ ((orow & 7) << 4))) = w8;
    }
    __syncthreads();

    #pragma unroll
    for (int si = 0; si < 4; ++si) {
        int strip = wv*4 + si;
        #pragma unroll
        for (int nt = 0; nt < 12; ++nt) {
            int orow = nt*16 + (lane & 15);
            f32x4 acc = {0.f,0.f,0.f,0.f};
            #pragma unroll
            for (int ks = 0; ks < 6; ++ks) {
                s16x8 bf = *(const s16x8*)(smem + orow*384 +
                              ((ks*64 + cb*16) ^ ((orow & 7) << 4)));
                acc = mfma16(af[si][ks], bf, acc);
            }
            #pragma unroll
            for (int r = 0; r < 4; ++r) {
                int trow = strip*16 + (lane >> 4)*4 + r;
                out_g[(size_t)w*49152 + trow*EMB + nt*16 + (lane & 15)] = acc[r];
            }
        }
    }
}

extern "C" void kernel_launch(void* const* d_in, const int* in_sizes, int n_in,
                              void* d_out, int out_size, void* d_ws, size_t ws_size,
                              hipStream_t stream) {
    (void)in_sizes; (void)n_in; (void)out_size; (void)d_ws; (void)ws_size;
    dwa_attn_kernel<<<dim3(NWIN), dim3(512), 0, stream>>>(
        (const float*)d_in[0],  (const float*)d_in[1],  (const float*)d_in[2],
        (const float*)d_in[3],  (const float*)d_in[4],  (const float*)d_in[5],
        (const float*)d_in[6],  (const float*)d_in[7],  (const float*)d_in[8],
        (const float*)d_in[9],  (const float*)d_in[10],
        (float*)d_out);
    dwa_proj_kernel<<<dim3(NWIN), dim3(256), 0, stream>>>(
        (const float*)d_in[11], (float*)d_out);
}

// Round 5
// 454.673 us; speedup vs baseline: 1.3616x; 1.3616x over previous
//
#include <hip/hip_runtime.h>

#define NWIN 1024
#define LTOK 256
#define EMB  192
#define NPAT 64
#define NHEAD 6
#define HDIM 32
#define SCALE 0.08838834764831845f
#define LN_EPS 1e-5f

typedef float f32x4 __attribute__((ext_vector_type(4)));
typedef short s16x8 __attribute__((ext_vector_type(8)));

// ---- attention kernel LDS layout (bytes) ----
#define OFF_KH  0        // [64 p][128 sc] bf16, row 256B, swz ((p&7)<<4)
#define OFF_VT  16384    // [128 sc][64 k] bf16, row 128B, swz ((sc&7)<<4)
#define OFF_PB  32768    // [64 q][64 k]  bf16, row 128B, swz ((q&7)<<4)
#define OFF_OB  40960    // [64 qp][2 hp][128 sc] bf16, row 512B, swz ((qp>>2)&3)<<5 ; phase1 partials
#define OFF_ST  73728    // stats: 6 x 64 f32
#define OFF_BH  75264    // bias_h: 225 f32 (pad 1024)
#define OFF_HB  76288    // halfbuf: [64 qr][2 half] float2 (m,s) = 1024B
#define SMEM_BYTES 77312 // -> 2 blocks/CU if VGPR<=128

__device__ __forceinline__ unsigned short f2bf(float f) {
    unsigned u = __float_as_uint(f);
    u += 0x7fffu + ((u >> 16) & 1u);
    return (unsigned short)(u >> 16);
}

__device__ __forceinline__ int tok_of(int p, int s) {
    // t = wh*32 + sh*16 + ww*2 + sw ; p = wh*8+ww, s = sh*2+sw
    return ((p >> 3) << 5) + ((s >> 1) << 4) + ((p & 7) << 1) + (s & 1);
}

__device__ __forceinline__ f32x4 mfma16(s16x8 a, s16x8 b, f32x4 c) {
    return __builtin_amdgcn_mfma_f32_16x16x32_bf16(a, b, c, 0, 0, 0);
}

__device__ __forceinline__ s16x8 ln_pack8r(const float* v, float mu, float rs,
                                           const float* __restrict__ wl,
                                           const float* __restrict__ bl,
                                           float scale) {
    f32x4 w0 = *(const f32x4*)wl;
    f32x4 w1 = *(const f32x4*)(wl + 4);
    f32x4 c0 = *(const f32x4*)bl;
    f32x4 c1 = *(const f32x4*)(bl + 4);
    s16x8 r;
    r[0] = (short)f2bf(((v[0]-mu)*rs*w0[0] + c0[0])*scale);
    r[1] = (short)f2bf(((v[1]-mu)*rs*w0[1] + c0[1])*scale);
    r[2] = (short)f2bf(((v[2]-mu)*rs*w0[2] + c0[2])*scale);
    r[3] = (short)f2bf(((v[3]-mu)*rs*w0[3] + c0[3])*scale);
    r[4] = (short)f2bf(((v[4]-mu)*rs*w1[0] + c1[0])*scale);
    r[5] = (short)f2bf(((v[5]-mu)*rs*w1[1] + c1[1])*scale);
    r[6] = (short)f2bf(((v[6]-mu)*rs*w1[2] + c1[2])*scale);
    r[7] = (short)f2bf(((v[7]-mu)*rs*w1[3] + c1[3])*scale);
    return r;
}

__device__ __forceinline__ void ln_f8r(const float* v, float mu, float rs,
                                       const float* __restrict__ wl,
                                       const float* __restrict__ bl,
                                       float* o) {
    f32x4 w0 = *(const f32x4*)wl;
    f32x4 w1 = *(const f32x4*)(wl + 4);
    f32x4 c0 = *(const f32x4*)bl;
    f32x4 c1 = *(const f32x4*)(bl + 4);
    o[0] = (v[0]-mu)*rs*w0[0] + c0[0];
    o[1] = (v[1]-mu)*rs*w0[1] + c0[1];
    o[2] = (v[2]-mu)*rs*w0[2] + c0[2];
    o[3] = (v[3]-mu)*rs*w0[3] + c0[3];
    o[4] = (v[4]-mu)*rs*w1[0] + c1[0];
    o[5] = (v[5]-mu)*rs*w1[1] + c1[1];
    o[6] = (v[6]-mu)*rs*w1[2] + c1[2];
    o[7] = (v[7]-mu)*rs*w1[3] + c1[3];
}

// mapping: p = tid&63 (lane-distinct -> conflict-free LDS), scb = (tid>>6)*2+i
__device__ __forceinline__ void load_T8(const float* __restrict__ g, size_t wbase,
                                        int tid, int hh, float pre[2][8]) {
    int p = tid & 63;
    #pragma unroll
    for (int i = 0; i < 2; ++i) {
        int scb = (tid >> 6) * 2 + i;
        int s = scb >> 2, cbx = scb & 3;
        int t = tok_of(p, s);
        const float* gp = g + wbase + t*EMB + hh*HDIM + cbx*8;
        *(f32x4*)&pre[i][0] = *(const f32x4*)gp;
        *(f32x4*)&pre[i][4] = *(const f32x4*)(gp + 4);
    }
}

__device__ __forceinline__ void stage_K(char* smem, int tid, int hh,
                                        const float kpre[2][8], const float* stats,
                                        const float* __restrict__ lnkw,
                                        const float* __restrict__ lnkb) {
    const float* muk = stats + 128; const float* rsk = stats + 192;
    int p = tid & 63;
    #pragma unroll
    for (int i = 0; i < 2; ++i) {
        int scb = (tid >> 6) * 2 + i;
        int s = scb >> 2, cbx = scb & 3;
        int chb = hh*HDIM + cbx*8;
        s16x8 kk = ln_pack8r(kpre[i], muk[p], rsk[p],
                             lnkw + s*EMB + chb, lnkb + s*EMB + chb, 1.0f);
        *(s16x8*)(smem + OFF_KH + p*256 + ((scb*16) ^ ((p & 7) << 4))) = kk;
    }
}

__device__ __forceinline__ void stage_V(char* smem, int tid, int hh,
                                        const float vpre[2][8], const float* stats,
                                        const float* __restrict__ lnvw,
                                        const float* __restrict__ lnvb) {
    const float* muv = stats + 256; const float* rsv = stats + 320;
    int p = tid & 63;
    #pragma unroll
    for (int i = 0; i < 2; ++i) {
        int scb = (tid >> 6) * 2 + i;
        int s = scb >> 2, cbx = scb & 3;
        int chb = hh*HDIM + cbx*8;
        float vn[8];
        ln_f8r(vpre[i], muv[p], rsv[p], lnvw + s*EMB + chb, lnvb + s*EMB + chb, vn);
        #pragma unroll
        for (int j = 0; j < 8; ++j) {
            int sc = scb*8 + j;   // = s*32 + cbx*8 + j
            // 64 lanes: same row sc, cols p*2 -> 2 lanes/bank = free
            *(unsigned short*)(smem + OFF_VT + sc*128 + ((p*2) ^ ((sc & 7) << 4)))
                = f2bf(vn[j]);
        }
    }
}

// Pre-projection bf16 rows live INSIDE d_out: window w, token t occupies
// bytes [w*196608 + t*768 + 384, +384). Stored as full 128B lines (head pairs).

__global__ __launch_bounds__(512, 2) void dwa_attn_kernel(
    const float* __restrict__ q_g, const float* __restrict__ k_g,
    const float* __restrict__ v_g, const float* __restrict__ mask_g,
    const float* __restrict__ lnqw, const float* __restrict__ lnqb,
    const float* __restrict__ lnkw, const float* __restrict__ lnkb,
    const float* __restrict__ lnvw, const float* __restrict__ lnvb,
    const float* __restrict__ btab, float* __restrict__ out_g)
{
    __shared__ __align__(16) char smem[SMEM_BYTES];

    const int tid  = threadIdx.x;
    const int lane = tid & 63;
    const int wv   = tid >> 6;
    const int win  = blockIdx.x;
    const size_t wbase = (size_t)win * LTOK * EMB;
    char* preb = (char*)out_g + (size_t)win * 196608;

    float* stats = (float*)(smem + OFF_ST);
    float* muq = stats;       float* rsq = stats + 64;
    float* biash = (float*)(smem + OFF_BH);
    float2* HB = (float2*)(smem + OFF_HB);

    const int mstrip = wv >> 1, nhalf = wv & 1;
    const int l15 = lane & 15, l4 = lane >> 4;
    const int pr = mstrip*16 + l15;
    const int cb = l4;

    // ---- per-lane mask regs + bias gather indices (QK^T D-reg mapping) ----
    const float* mask_w = mask_g + (size_t)(win & 63) * NPAT * NPAT;
    const int kc0 = nhalf*32 + l15, kc1 = kc0 + 16;
    float mm0[4], mm1[4];
    int idx0[4], idx1[4];
    {
        int kh0 = kc0 >> 3, kw0 = kc0 & 7, kh1 = kc1 >> 3, kw1 = kc1 & 7;
        #pragma unroll
        for (int r = 0; r < 4; ++r) {
            int qr = mstrip*16 + l4*4 + r;
            mm0[r] = mask_w[qr*64 + kc0];
            mm1[r] = mask_w[qr*64 + kc1];
            idx0[r] = ((qr>>3) - kh0 + 7)*15 + ((qr&7) - kw0 + 7);
            idx1[r] = ((qr>>3) - kh1 + 7)*15 + ((qr&7) - kw1 + 7);
        }
    }

    // ---------------- Phase 1: LN stats for q,k,v (single pass) ----------------
    {
        float* part = (float*)(smem + OFF_OB);   // [256 t][2 half][6]
        const int t = tid >> 1, half = tid & 1;
        const f32x4* qp = (const f32x4*)(q_g + wbase + t*EMB + half*96);
        const f32x4* kp = (const f32x4*)(k_g + wbase + t*EMB + half*96);
        const f32x4* vp = (const f32x4*)(v_g + wbase + t*EMB + half*96);
        float s1q=0.f,s2q=0.f,s1k=0.f,s2k=0.f,s1v=0.f,s2v=0.f;
        #pragma unroll 4
        for (int i = 0; i < 24; ++i) {
            f32x4 a = qp[i];
            s1q += a[0]+a[1]+a[2]+a[3];
            s2q += a[0]*a[0]+a[1]*a[1]+a[2]*a[2]+a[3]*a[3];
            f32x4 b = kp[i];
            s1k += b[0]+b[1]+b[2]+b[3];
            s2k += b[0]*b[0]+b[1]*b[1]+b[2]*b[2]+b[3]*b[3];
            f32x4 c = vp[i];
            s1v += c[0]+c[1]+c[2]+c[3];
            s2v += c[0]*c[0]+c[1]*c[1]+c[2]*c[2]+c[3]*c[3];
        }
        float* pp = part + (t*2 + half)*6;
        pp[0]=s1q; pp[1]=s2q; pp[2]=s1k; pp[3]=s2k; pp[4]=s1v; pp[5]=s2v;
        __syncthreads();
        if (tid < NPAT) {
            float S[6] = {0.f,0.f,0.f,0.f,0.f,0.f};
            #pragma unroll
            for (int s = 0; s < 4; ++s) {
                int tt = tok_of(tid, s);
                const float* pr_ = part + tt*12;
                #pragma unroll
                for (int x = 0; x < 6; ++x) S[x] += pr_[x] + pr_[6 + x];
            }
            #pragma unroll
            for (int x = 0; x < 3; ++x) {
                float mu  = S[2*x] * (1.f/768.f);
                float var = S[2*x+1] * (1.f/768.f) - mu*mu;
                stats[x*128 + tid]      = mu;
                stats[x*128 + 64 + tid] = rsqrtf(var + LN_EPS);
            }
        }
        __syncthreads();
    }

    // ---------------- Prologue: stage K/V/bias for head 0 ----------------
    float kpre[2][8], vpre[2][8];
    float breg;
    load_T8(k_g, wbase, tid, 0, kpre);
    load_T8(v_g, wbase, tid, 0, vpre);
    breg = (tid < 225) ? btab[tid * NHEAD] : 0.f;
    stage_K(smem, tid, 0, kpre, stats, lnkw, lnkb);
    stage_V(smem, tid, 0, vpre, stats, lnvw, lnvb);
    if (tid < 225) biash[tid] = breg;
    __syncthreads();

    // ---------------- Head loop: 3 barriers per head ----------------
    for (int h = 0; h < NHEAD; ++h) {
        const bool pf = (h < NHEAD-1);
        // step1: issue K/V/bias prefetch for h+1
        if (pf) {
            load_T8(k_g, wbase, tid, h+1, kpre);
            load_T8(v_g, wbase, tid, h+1, vpre);
            breg = (tid < 225) ? btab[tid*NHEAD + h + 1] : 0.f;
        }

        // step2: QK^T (Q loaded inline; L3/L2-hot) + in-register softmax half-reduce
        float e0[4], e1[4], mrow[4];
        {
            float mu = muq[pr], rs = rsq[pr];
            const float* qbase = q_g + wbase + h*HDIM + cb*8;
            f32x4 acc0 = {0.f,0.f,0.f,0.f};
            f32x4 acc1 = {0.f,0.f,0.f,0.f};
            #pragma unroll
            for (int ks = 0; ks < 4; ++ks) {
                int t = tok_of(pr, ks);
                float qv[8];
                *(f32x4*)&qv[0] = *(const f32x4*)(qbase + t*EMB);
                *(f32x4*)&qv[4] = *(const f32x4*)(qbase + t*EMB + 4);
                int chb = h*HDIM + cb*8;
                s16x8 af = ln_pack8r(qv, mu, rs,
                                     lnqw + ks*EMB + chb, lnqb + ks*EMB + chb, SCALE);
                {
                    int row = nhalf*32 + l15;
                    s16x8 bf = *(const s16x8*)(smem + OFF_KH + row*256 +
                                  ((ks*64 + cb*16) ^ ((row & 7) << 4)));
                    acc0 = mfma16(af, bf, acc0);
                }
                {
                    int row = nhalf*32 + 16 + l15;
                    s16x8 bf = *(const s16x8*)(smem + OFF_KH + row*256 +
                                  ((ks*64 + cb*16) ^ ((row & 7) << 4)));
                    acc1 = mfma16(af, bf, acc1);
                }
            }
            float srow[4];
            #pragma unroll
            for (int r = 0; r < 4; ++r) {
                float L0 = acc0[r] + mm0[r] + biash[idx0[r]];
                float L1 = acc1[r] + mm1[r] + biash[idx1[r]];
                float m = fmaxf(L0, L1);
                m = fmaxf(m, __shfl_xor(m, 1));
                m = fmaxf(m, __shfl_xor(m, 2));
                m = fmaxf(m, __shfl_xor(m, 4));
                m = fmaxf(m, __shfl_xor(m, 8));
                float a = __expf(L0 - m), b = __expf(L1 - m);
                float s = a + b;
                s += __shfl_xor(s, 1);
                s += __shfl_xor(s, 2);
                s += __shfl_xor(s, 4);
                s += __shfl_xor(s, 8);
                e0[r] = a; e1[r] = b; mrow[r] = m; srow[r] = s;
            }
            if (l15 == 0) {
                #pragma unroll
                for (int r = 0; r < 4; ++r) {
                    float2 v; v.x = mrow[r]; v.y = srow[r];
                    HB[(mstrip*16 + l4*4 + r)*2 + nhalf] = v;
                }
            }
        }
        __syncthreads();   // A: halves ready; KH reads done; bias reads done

        // step3: restage KH/bias for h+1; finalize P -> PB
        if (pf) {
            stage_K(smem, tid, h+1, kpre, stats, lnkw, lnkb);
            if (tid < 225) biash[tid] = breg;
        }
        #pragma unroll
        for (int r = 0; r < 4; ++r) {
            int qr = mstrip*16 + l4*4 + r;
            float2 ha = HB[qr*2 + 0], hb = HB[qr*2 + 1];
            float M = fmaxf(ha.x, hb.x);
            float tot = ha.y*__expf(ha.x - M) + hb.y*__expf(hb.x - M);
            float f = __expf(mrow[r] - M) / tot;
            unsigned short p0 = f2bf(e0[r]*f);
            unsigned short p1 = f2bf(e1[r]*f);
            *(unsigned short*)(smem + OFF_PB + qr*128 + ((kc0*2) ^ ((qr & 7) << 4))) = p0;
            *(unsigned short*)(smem + OFF_PB + qr*128 + ((kc1*2) ^ ((qr & 7) << 4))) = p1;
        }
        __syncthreads();   // B: PB ready; KH(h+1)/bias(h+1) staged

        // step5: P @ V -> OB[h&1]
        {
            s16x8 ap0 = *(const s16x8*)(smem + OFF_PB + pr*128 +
                          ((cb*16) ^ ((pr & 7) << 4)));
            s16x8 ap1 = *(const s16x8*)(smem + OFF_PB + pr*128 +
                          ((64 + cb*16) ^ ((pr & 7) << 4)));
            __builtin_amdgcn_s_setprio(1);
            #pragma unroll
            for (int i = 0; i < 4; ++i) {
                int nt = nhalf*4 + i;
                int brow = nt*16 + l15;     // sc
                f32x4 acc = {0.f,0.f,0.f,0.f};
                s16x8 bf0 = *(const s16x8*)(smem + OFF_VT + brow*128 +
                              ((cb*16) ^ ((brow & 7) << 4)));
                s16x8 bf1 = *(const s16x8*)(smem + OFF_VT + brow*128 +
                              ((64 + cb*16) ^ ((brow & 7) << 4)));
                acc = mfma16(ap0, bf0, acc);
                acc = mfma16(ap1, bf1, acc);
                int sc = nt*16 + l15;
                #pragma unroll
                for (int r = 0; r < 4; ++r) {
                    int qp = mstrip*16 + l4*4 + r;
                    *(unsigned short*)(smem + OFF_OB + qp*512 +
                        (((h & 1)*256 + sc*2) ^ (((qp >> 2) & 3) << 5))) = f2bf(acc[r]);
                }
            }
            __builtin_amdgcn_s_setprio(0);
        }
        __syncthreads();   // C: OB ready; VT reads done

        // step6: every 2nd head, store full 128B/token head-pair lines
        if (h & 1) {
            int hpair = h >> 1;
            #pragma unroll
            for (int i = 0; i < 4; ++i) {
                int c = i*512 + tid;             // 2048 chunks of 16B
                int t = c >> 3, ch8 = c & 7;
                int hp = ch8 >> 2, c2b = ch8 & 3;
                int qp = ((t >> 5) << 3) | ((t >> 1) & 7);
                int s  = (((t >> 4) & 1) << 1) | (t & 1);
                s16x8 v = *(const s16x8*)(smem + OFF_OB + qp*512 +
                              ((hp*256 + s*64 + c2b*16) ^ (((qp >> 2) & 3) << 5)));
                *(s16x8*)(preb + (size_t)t*768 + 384 + hpair*128 + hp*64 + c2b*16) = v;
            }
        }
        // step7: restage VT for h+1 (reads done at C; next read after h+1's B)
        if (pf) stage_V(smem, tid, h+1, vpre, stats, lnvw, lnvb);
        // no barrier here: VT/PB/KH/bias next touched only after h+1's A/B
    }
}

// ---- projection: 1 block per window, W staged bf16 in LDS once ----
__global__ __launch_bounds__(256, 2) void dwa_proj_kernel(
    const float* __restrict__ pw, float* __restrict__ out_g)
{
    __shared__ __align__(16) char smem[73728];   // [192 orow][192 ch] bf16, swz

    const int tid  = threadIdx.x;
    const int lane = tid & 63;
    const int wv   = tid >> 6;
    const int w    = blockIdx.x;
    const char* preb = (const char*)out_g + (size_t)w * 196608;
    const int cb = lane >> 4;

    // preload all A fragments (issued before staging; overlaps W stage + barrier)
    s16x8 af[4][6];
    #pragma unroll
    for (int si = 0; si < 4; ++si) {
        int strip = wv*4 + si;
        int arow = strip*16 + (lane & 15);
        #pragma unroll
        for (int ks = 0; ks < 6; ++ks)
            af[si][ks] = *(const s16x8*)(preb + (size_t)arow*768 + 384 + ks*64 + cb*16);
    }

    // stage W (192x192 f32 -> bf16), 4608 chunks of 8
    #pragma unroll 2
    for (int i = 0; i < 18; ++i) {
        int c = i*256 + tid;
        int orow = c / 24, cb8 = c % 24;
        const float* wp = pw + (size_t)orow*EMB + cb8*8;
        f32x4 a = *(const f32x4*)wp;
        f32x4 b = *(const f32x4*)(wp + 4);
        s16x8 w8;
        w8[0] = (short)f2bf(a[0]); w8[1] = (short)f2bf(a[1]);
        w8[2] = (short)f2bf(a[2]); w8[3] = (short)f2bf(a[3]);
        w8[4] = (short)f2bf(b[0]); w8[5] = (short)f2bf(b[1]);
        w8[6] = (short)f2bf(b[2]); w8[7] = (short)f2bf(b[3]);
        *(s16x8*)(smem + orow*384 + ((cb8*16) ^ ((orow & 7) << 4))) = w8;
    }
    __syncthreads();

    #pragma unroll
    for (int si = 0; si < 4; ++si) {
        int strip = wv*4 + si;
        #pragma unroll
        for (int nt = 0; nt < 12; ++nt) {
            int orow = nt*16 + (lane & 15);
            f32x4 acc = {0.f,0.f,0.f,0.f};
            #pragma unroll
            for (int ks = 0; ks < 6; ++ks) {
                s16x8 bf = *(const s16x8*)(smem + orow*384 +
                              ((ks*64 + cb*16) ^ ((orow & 7) << 4)));
                acc = mfma16(af[si][ks], bf, acc);
            }
            #pragma unroll
            for (int r = 0; r < 4; ++r) {
                int trow = strip*16 + (lane >> 4)*4 + r;
                out_g[(size_t)w*49152 + trow*EMB + nt*16 + (lane & 15)] = acc[r];
            }
        }
    }
}

extern "C" void kernel_launch(void* const* d_in, const int* in_sizes, int n_in,
                              void* d_out, int out_size, void* d_ws, size_t ws_size,
                              hipStream_t stream) {
    (void)in_sizes; (void)n_in; (void)out_size; (void)d_ws; (void)ws_size;
    dwa_attn_kernel<<<dim3(NWIN), dim3(512), 0, stream>>>(
        (const float*)d_in[0],  (const float*)d_in[1],  (const float*)d_in[2],
        (const float*)d_in[3],  (const float*)d_in[4],  (const float*)d_in[5],
        (const float*)d_in[6],  (const float*)d_in[7],  (const float*)d_in[8],
        (const float*)d_in[9],  (const float*)d_in[10],
        (float*)d_out);
    dwa_proj_kernel<<<dim3(NWIN), dim3(256), 0, stream>>>(
        (const float*)d_in[11], (float*)d_out);
}

// Round 6
// 452.010 us; speedup vs baseline: 1.3697x; 1.0059x over previous
//
#include <hip/hip_runtime.h>

#define NWIN 1024
#define LTOK 256
#define EMB  192
#define NPAT 64
#define NHEAD 6
#define HDIM 32
#define SCALE 0.08838834764831845f
#define LN_EPS 1e-5f

typedef float f32x4 __attribute__((ext_vector_type(4)));
typedef short s16x8 __attribute__((ext_vector_type(8)));

// ---- attention kernel LDS layout (bytes) ----
#define OFF_KH  0        // [64 p][128 sc] bf16, row 256B, swz ((p&7)<<4)
#define OFF_VT  16384    // [128 sc][64 k] bf16, row 128B, swz ((sc&7)<<4)
#define OFF_PB  32768    // [64 q][64 k]  bf16, row 128B, swz ((q&7)<<4)
#define OFF_OB  40960    // [64 qp] x 264B rows (128 sc bf16 + 8B pad) ; phase1 partials
#define OFF_ST  57856    // stats: 6 x 64 f32
#define OFF_BH  59392    // bias_h: 225 f32 (pad 1024)
#define OFF_HB  60416    // halfbuf: [64 qr][2 half] float2 (m,s) = 1024B
#define SMEM_BYTES 61440 // <= 60KB -> 2 blocks/CU (proven at 60.9KB in R2)
#define OBSTRIDE 264

__device__ __forceinline__ unsigned short f2bf(float f) {
    unsigned u = __float_as_uint(f);
    u += 0x7fffu + ((u >> 16) & 1u);
    return (unsigned short)(u >> 16);
}

__device__ __forceinline__ int tok_of(int p, int s) {
    // t = wh*32 + sh*16 + ww*2 + sw ; p = wh*8+ww, s = sh*2+sw
    return ((p >> 3) << 5) + ((s >> 1) << 4) + ((p & 7) << 1) + (s & 1);
}

__device__ __forceinline__ f32x4 mfma16(s16x8 a, s16x8 b, f32x4 c) {
    return __builtin_amdgcn_mfma_f32_16x16x32_bf16(a, b, c, 0, 0, 0);
}

__device__ __forceinline__ s16x8 ln_pack8r(const float* v, float mu, float rs,
                                           const float* __restrict__ wl,
                                           const float* __restrict__ bl,
                                           float scale) {
    f32x4 w0 = *(const f32x4*)wl;
    f32x4 w1 = *(const f32x4*)(wl + 4);
    f32x4 c0 = *(const f32x4*)bl;
    f32x4 c1 = *(const f32x4*)(bl + 4);
    s16x8 r;
    r[0] = (short)f2bf(((v[0]-mu)*rs*w0[0] + c0[0])*scale);
    r[1] = (short)f2bf(((v[1]-mu)*rs*w0[1] + c0[1])*scale);
    r[2] = (short)f2bf(((v[2]-mu)*rs*w0[2] + c0[2])*scale);
    r[3] = (short)f2bf(((v[3]-mu)*rs*w0[3] + c0[3])*scale);
    r[4] = (short)f2bf(((v[4]-mu)*rs*w1[0] + c1[0])*scale);
    r[5] = (short)f2bf(((v[5]-mu)*rs*w1[1] + c1[1])*scale);
    r[6] = (short)f2bf(((v[6]-mu)*rs*w1[2] + c1[2])*scale);
    r[7] = (short)f2bf(((v[7]-mu)*rs*w1[3] + c1[3])*scale);
    return r;
}

__device__ __forceinline__ void ln_f8r(const float* v, float mu, float rs,
                                       const float* __restrict__ wl,
                                       const float* __restrict__ bl,
                                       float* o) {
    f32x4 w0 = *(const f32x4*)wl;
    f32x4 w1 = *(const f32x4*)(wl + 4);
    f32x4 c0 = *(const f32x4*)bl;
    f32x4 c1 = *(const f32x4*)(bl + 4);
    o[0] = (v[0]-mu)*rs*w0[0] + c0[0];
    o[1] = (v[1]-mu)*rs*w0[1] + c0[1];
    o[2] = (v[2]-mu)*rs*w0[2] + c0[2];
    o[3] = (v[3]-mu)*rs*w0[3] + c0[3];
    o[4] = (v[4]-mu)*rs*w1[0] + c1[0];
    o[5] = (v[5]-mu)*rs*w1[1] + c1[1];
    o[6] = (v[6]-mu)*rs*w1[2] + c1[2];
    o[7] = (v[7]-mu)*rs*w1[3] + c1[3];
}

// mapping: p = tid&63 (lane-distinct -> conflict-free LDS), scb = (tid>>6)*2+i
__device__ __forceinline__ void load_T8(const float* __restrict__ g, size_t wbase,
                                        int tid, int hh, float pre[2][8]) {
    int p = tid & 63;
    #pragma unroll
    for (int i = 0; i < 2; ++i) {
        int scb = (tid >> 6) * 2 + i;
        int s = scb >> 2, cbx = scb & 3;
        int t = tok_of(p, s);
        const float* gp = g + wbase + t*EMB + hh*HDIM + cbx*8;
        *(f32x4*)&pre[i][0] = *(const f32x4*)gp;
        *(f32x4*)&pre[i][4] = *(const f32x4*)(gp + 4);
    }
}

__device__ __forceinline__ void stage_K(char* smem, int tid, int hh,
                                        const float kpre[2][8], const float* stats,
                                        const float* __restrict__ lnkw,
                                        const float* __restrict__ lnkb) {
    const float* muk = stats + 128; const float* rsk = stats + 192;
    int p = tid & 63;
    #pragma unroll
    for (int i = 0; i < 2; ++i) {
        int scb = (tid >> 6) * 2 + i;
        int s = scb >> 2, cbx = scb & 3;
        int chb = hh*HDIM + cbx*8;
        s16x8 kk = ln_pack8r(kpre[i], muk[p], rsk[p],
                             lnkw + s*EMB + chb, lnkb + s*EMB + chb, 1.0f);
        *(s16x8*)(smem + OFF_KH + p*256 + ((scb*16) ^ ((p & 7) << 4))) = kk;
    }
}

__device__ __forceinline__ void stage_V(char* smem, int tid, int hh,
                                        const float vpre[2][8], const float* stats,
                                        const float* __restrict__ lnvw,
                                        const float* __restrict__ lnvb) {
    const float* muv = stats + 256; const float* rsv = stats + 320;
    int p = tid & 63;
    #pragma unroll
    for (int i = 0; i < 2; ++i) {
        int scb = (tid >> 6) * 2 + i;
        int s = scb >> 2, cbx = scb & 3;
        int chb = hh*HDIM + cbx*8;
        float vn[8];
        ln_f8r(vpre[i], muv[p], rsv[p], lnvw + s*EMB + chb, lnvb + s*EMB + chb, vn);
        #pragma unroll
        for (int j = 0; j < 8; ++j) {
            int sc = scb*8 + j;   // = s*32 + cbx*8 + j
            // 64 lanes: same row sc, cols p*2 -> 2 lanes/bank = free
            *(unsigned short*)(smem + OFF_VT + sc*128 + ((p*2) ^ ((sc & 7) << 4)))
                = f2bf(vn[j]);
        }
    }
}

// Pre-projection bf16 lives INSIDE d_out: window w bytes [w*196608+98304, +98304)
// layout [h:6][qp:64][sc:128] bf16 (16384B per head, 256B per qp row -> full-line
// stores, no RFO). proj reads all of it into regs before overwriting with f32.

__global__ __launch_bounds__(512, 2) void dwa_attn_kernel(
    const float* __restrict__ q_g, const float* __restrict__ k_g,
    const float* __restrict__ v_g, const float* __restrict__ mask_g,
    const float* __restrict__ lnqw, const float* __restrict__ lnqb,
    const float* __restrict__ lnkw, const float* __restrict__ lnkb,
    const float* __restrict__ lnvw, const float* __restrict__ lnvb,
    const float* __restrict__ btab, float* __restrict__ out_g)
{
    __shared__ __align__(16) char smem[SMEM_BYTES];

    const int tid  = threadIdx.x;
    const int lane = tid & 63;
    const int wv   = tid >> 6;
    const int win  = blockIdx.x;
    const size_t wbase = (size_t)win * LTOK * EMB;
    char* preb = (char*)out_g + (size_t)win * 196608 + 98304;

    float* stats = (float*)(smem + OFF_ST);
    float* muq = stats;       float* rsq = stats + 64;
    float* biash = (float*)(smem + OFF_BH);
    float2* HB = (float2*)(smem + OFF_HB);

    const int mstrip = wv >> 1, nhalf = wv & 1;
    const int l15 = lane & 15, l4 = lane >> 4;
    const int pr = mstrip*16 + l15;
    const int cb = l4;

    // ---- per-lane mask regs + bias gather indices (QK^T D-reg mapping) ----
    const float* mask_w = mask_g + (size_t)(win & 63) * NPAT * NPAT;
    const int kc0 = nhalf*32 + l15, kc1 = kc0 + 16;
    float mm0[4], mm1[4];
    int idx0[4], idx1[4];
    {
        int kh0 = kc0 >> 3, kw0 = kc0 & 7, kh1 = kc1 >> 3, kw1 = kc1 & 7;
        #pragma unroll
        for (int r = 0; r < 4; ++r) {
            int qr = mstrip*16 + l4*4 + r;
            mm0[r] = mask_w[qr*64 + kc0];
            mm1[r] = mask_w[qr*64 + kc1];
            idx0[r] = ((qr>>3) - kh0 + 7)*15 + ((qr&7) - kw0 + 7);
            idx1[r] = ((qr>>3) - kh1 + 7)*15 + ((qr&7) - kw1 + 7);
        }
    }

    // ---------------- Phase 1: LN stats for q,k,v (single pass) ----------------
    {
        float* part = (float*)(smem + OFF_OB);   // [256 t][2 half][6] = 12KB
        const int t = tid >> 1, half = tid & 1;
        const f32x4* qp = (const f32x4*)(q_g + wbase + t*EMB + half*96);
        const f32x4* kp = (const f32x4*)(k_g + wbase + t*EMB + half*96);
        const f32x4* vp = (const f32x4*)(v_g + wbase + t*EMB + half*96);
        float s1q=0.f,s2q=0.f,s1k=0.f,s2k=0.f,s1v=0.f,s2v=0.f;
        #pragma unroll 4
        for (int i = 0; i < 24; ++i) {
            f32x4 a = qp[i];
            s1q += a[0]+a[1]+a[2]+a[3];
            s2q += a[0]*a[0]+a[1]*a[1]+a[2]*a[2]+a[3]*a[3];
            f32x4 b = kp[i];
            s1k += b[0]+b[1]+b[2]+b[3];
            s2k += b[0]*b[0]+b[1]*b[1]+b[2]*b[2]+b[3]*b[3];
            f32x4 c = vp[i];
            s1v += c[0]+c[1]+c[2]+c[3];
            s2v += c[0]*c[0]+c[1]*c[1]+c[2]*c[2]+c[3]*c[3];
        }
        float* pp = part + (t*2 + half)*6;
        pp[0]=s1q; pp[1]=s2q; pp[2]=s1k; pp[3]=s2k; pp[4]=s1v; pp[5]=s2v;
        __syncthreads();
        if (tid < NPAT) {
            float S[6] = {0.f,0.f,0.f,0.f,0.f,0.f};
            #pragma unroll
            for (int s = 0; s < 4; ++s) {
                int tt = tok_of(tid, s);
                const float* pr_ = part + tt*12;
                #pragma unroll
                for (int x = 0; x < 6; ++x) S[x] += pr_[x] + pr_[6 + x];
            }
            #pragma unroll
            for (int x = 0; x < 3; ++x) {
                float mu  = S[2*x] * (1.f/768.f);
                float var = S[2*x+1] * (1.f/768.f) - mu*mu;
                stats[x*128 + tid]      = mu;
                stats[x*128 + 64 + tid] = rsqrtf(var + LN_EPS);
            }
        }
        __syncthreads();
    }

    // ---------------- Prologue: stage K/V/bias for head 0 ----------------
    float kpre[2][8], vpre[2][8];
    float breg;
    load_T8(k_g, wbase, tid, 0, kpre);
    load_T8(v_g, wbase, tid, 0, vpre);
    breg = (tid < 225) ? btab[tid * NHEAD] : 0.f;
    stage_K(smem, tid, 0, kpre, stats, lnkw, lnkb);
    stage_V(smem, tid, 0, vpre, stats, lnvw, lnvb);
    if (tid < 225) biash[tid] = breg;
    __syncthreads();

    // ---------------- Head loop: 3 barriers per head ----------------
    for (int h = 0; h < NHEAD; ++h) {
        const bool pf = (h < NHEAD-1);
        // step1: issue K/V/bias prefetch for h+1
        if (pf) {
            load_T8(k_g, wbase, tid, h+1, kpre);
            load_T8(v_g, wbase, tid, h+1, vpre);
            breg = (tid < 225) ? btab[tid*NHEAD + h + 1] : 0.f;
        }

        // step2: QK^T (Q loaded inline; L3/L2-hot) + in-register softmax half-reduce
        float e0[4], e1[4], mrow[4];
        {
            float mu = muq[pr], rs = rsq[pr];
            const float* qbase = q_g + wbase + h*HDIM + cb*8;
            f32x4 acc0 = {0.f,0.f,0.f,0.f};
            f32x4 acc1 = {0.f,0.f,0.f,0.f};
            #pragma unroll
            for (int ks = 0; ks < 4; ++ks) {
                int t = tok_of(pr, ks);
                float qv[8];
                *(f32x4*)&qv[0] = *(const f32x4*)(qbase + t*EMB);
                *(f32x4*)&qv[4] = *(const f32x4*)(qbase + t*EMB + 4);
                int chb = h*HDIM + cb*8;
                s16x8 af = ln_pack8r(qv, mu, rs,
                                     lnqw + ks*EMB + chb, lnqb + ks*EMB + chb, SCALE);
                {
                    int row = nhalf*32 + l15;
                    s16x8 bf = *(const s16x8*)(smem + OFF_KH + row*256 +
                                  ((ks*64 + cb*16) ^ ((row & 7) << 4)));
                    acc0 = mfma16(af, bf, acc0);
                }
                {
                    int row = nhalf*32 + 16 + l15;
                    s16x8 bf = *(const s16x8*)(smem + OFF_KH + row*256 +
                                  ((ks*64 + cb*16) ^ ((row & 7) << 4)));
                    acc1 = mfma16(af, bf, acc1);
                }
            }
            float srow[4];
            #pragma unroll
            for (int r = 0; r < 4; ++r) {
                float L0 = acc0[r] + mm0[r] + biash[idx0[r]];
                float L1 = acc1[r] + mm1[r] + biash[idx1[r]];
                float m = fmaxf(L0, L1);
                m = fmaxf(m, __shfl_xor(m, 1));
                m = fmaxf(m, __shfl_xor(m, 2));
                m = fmaxf(m, __shfl_xor(m, 4));
                m = fmaxf(m, __shfl_xor(m, 8));
                float a = __expf(L0 - m), b = __expf(L1 - m);
                float s = a + b;
                s += __shfl_xor(s, 1);
                s += __shfl_xor(s, 2);
                s += __shfl_xor(s, 4);
                s += __shfl_xor(s, 8);
                e0[r] = a; e1[r] = b; mrow[r] = m; srow[r] = s;
            }
            if (l15 == 0) {
                #pragma unroll
                for (int r = 0; r < 4; ++r) {
                    float2 v; v.x = mrow[r]; v.y = srow[r];
                    HB[(mstrip*16 + l4*4 + r)*2 + nhalf] = v;
                }
            }
        }
        __syncthreads();   // A: halves ready; KH reads done; bias reads done

        // step3: restage KH/bias for h+1; finalize P -> PB
        if (pf) {
            stage_K(smem, tid, h+1, kpre, stats, lnkw, lnkb);
            if (tid < 225) biash[tid] = breg;
        }
        #pragma unroll
        for (int r = 0; r < 4; ++r) {
            int qr = mstrip*16 + l4*4 + r;
            float2 ha = HB[qr*2 + 0], hb = HB[qr*2 + 1];
            float M = fmaxf(ha.x, hb.x);
            float tot = ha.y*__expf(ha.x - M) + hb.y*__expf(hb.x - M);
            float f = __expf(mrow[r] - M) / tot;
            unsigned short p0 = f2bf(e0[r]*f);
            unsigned short p1 = f2bf(e1[r]*f);
            *(unsigned short*)(smem + OFF_PB + qr*128 + ((kc0*2) ^ ((qr & 7) << 4))) = p0;
            *(unsigned short*)(smem + OFF_PB + qr*128 + ((kc1*2) ^ ((qr & 7) << 4))) = p1;
        }
        __syncthreads();   // B: PB ready; KH(h+1)/bias(h+1) staged

        // step5: P @ V -> OB (single head, [qp] rows of 264B stagger)
        {
            s16x8 ap0 = *(const s16x8*)(smem + OFF_PB + pr*128 +
                          ((cb*16) ^ ((pr & 7) << 4)));
            s16x8 ap1 = *(const s16x8*)(smem + OFF_PB + pr*128 +
                          ((64 + cb*16) ^ ((pr & 7) << 4)));
            __builtin_amdgcn_s_setprio(1);
            #pragma unroll
            for (int i = 0; i < 4; ++i) {
                int nt = nhalf*4 + i;
                int brow = nt*16 + l15;     // sc
                f32x4 acc = {0.f,0.f,0.f,0.f};
                s16x8 bf0 = *(const s16x8*)(smem + OFF_VT + brow*128 +
                              ((cb*16) ^ ((brow & 7) << 4)));
                s16x8 bf1 = *(const s16x8*)(smem + OFF_VT + brow*128 +
                              ((64 + cb*16) ^ ((brow & 7) << 4)));
                acc = mfma16(ap0, bf0, acc);
                acc = mfma16(ap1, bf1, acc);
                int sc = nt*16 + l15;
                #pragma unroll
                for (int r = 0; r < 4; ++r) {
                    int qp = mstrip*16 + l4*4 + r;
                    *(unsigned short*)(smem + OFF_OB + qp*OBSTRIDE + sc*2) = f2bf(acc[r]);
                }
            }
            __builtin_amdgcn_s_setprio(0);
        }
        __syncthreads();   // C: OB ready; VT reads done

        // step6: store this head's [qp][sc] slab as full 256B rows (no RFO)
        #pragma unroll
        for (int i = 0; i < 2; ++i) {
            int c = i*512 + tid;             // 1024 chunks of 16B
            int qp = c >> 4, ch = c & 15;
            s16x8 v = *(const s16x8*)(smem + OFF_OB + qp*OBSTRIDE + ch*16);
            *(s16x8*)(preb + h*16384 + qp*256 + ch*16) = v;
        }
        // step7: restage VT for h+1 (reads done at C; next read after h+1's B)
        if (pf) stage_V(smem, tid, h+1, vpre, stats, lnvw, lnvb);
        // no barrier: OB next written after h+1's A/B; VT next read after h+1's B
    }
}

// ---- projection: 1 block per window, W staged bf16 in LDS once ----
__global__ __launch_bounds__(256, 2) void dwa_proj_kernel(
    const float* __restrict__ pw, float* __restrict__ out_g)
{
    __shared__ __align__(16) char smem[73728];   // [192 orow][192 ch] bf16, swz

    const int tid  = threadIdx.x;
    const int lane = tid & 63;
    const int wv   = tid >> 6;
    const int w    = blockIdx.x;
    const char* preb = (const char*)out_g + (size_t)w * 196608 + 98304;
    const int cb = lane >> 4;

    // preload all A fragments from [h][qp][sc] pre layout (before staging barrier)
    s16x8 af[4][6];
    #pragma unroll
    for (int si = 0; si < 4; ++si) {
        int t = (wv*4 + si)*16 + (lane & 15);       // token row
        int qp = ((t >> 5) << 3) | ((t >> 1) & 7);
        int s  = (((t >> 4) & 1) << 1) | (t & 1);
        #pragma unroll
        for (int ks = 0; ks < 6; ++ks)
            af[si][ks] = *(const s16x8*)(preb + ks*16384 + qp*256 + s*64 + cb*16);
    }

    // stage W (192x192 f32 -> bf16), 4608 chunks of 8
    #pragma unroll 2
    for (int i = 0; i < 18; ++i) {
        int c = i*256 + tid;
        int orow = c / 24, cb8 = c % 24;
        const float* wp = pw + (size_t)orow*EMB + cb8*8;
        f32x4 a = *(const f32x4*)wp;
        f32x4 b = *(const f32x4*)(wp + 4);
        s16x8 w8;
        w8[0] = (short)f2bf(a[0]); w8[1] = (short)f2bf(a[1]);
        w8[2] = (short)f2bf(a[2]); w8[3] = (short)f2bf(a[3]);
        w8[4] = (short)f2bf(b[0]); w8[5] = (short)f2bf(b[1]);
        w8[6] = (short)f2bf(b[2]); w8[7] = (short)f2bf(b[3]);
        *(s16x8*)(smem + orow*384 + ((cb8*16) ^ ((orow & 7) << 4))) = w8;
    }
    __syncthreads();

    #pragma unroll
    for (int si = 0; si < 4; ++si) {
        int strip = wv*4 + si;
        #pragma unroll
        for (int nt = 0; nt < 12; ++nt) {
            int orow = nt*16 + (lane & 15);
            f32x4 acc = {0.f,0.f,0.f,0.f};
            #pragma unroll
            for (int ks = 0; ks < 6; ++ks) {
                s16x8 bf = *(const s16x8*)(smem + orow*384 +
                              ((ks*64 + cb*16) ^ ((orow & 7) << 4)));
                acc = mfma16(af[si][ks], bf, acc);
            }
            #pragma unroll
            for (int r = 0; r < 4; ++r) {
                int trow = strip*16 + (lane >> 4)*4 + r;
                out_g[(size_t)w*49152 + trow*EMB + nt*16 + (lane & 15)] = acc[r];
            }
        }
    }
}

extern "C" void kernel_launch(void* const* d_in, const int* in_sizes, int n_in,
                              void* d_out, int out_size, void* d_ws, size_t ws_size,
                              hipStream_t stream) {
    (void)in_sizes; (void)n_in; (void)out_size; (void)d_ws; (void)ws_size;
    dwa_attn_kernel<<<dim3(NWIN), dim3(512), 0, stream>>>(
        (const float*)d_in[0],  (const float*)d_in[1],  (const float*)d_in[2],
        (const float*)d_in[3],  (const float*)d_in[4],  (const float*)d_in[5],
        (const float*)d_in[6],  (const float*)d_in[7],  (const float*)d_in[8],
        (const float*)d_in[9],  (const float*)d_in[10],
        (float*)d_out);
    dwa_proj_kernel<<<dim3(NWIN), dim3(256), 0, stream>>>(
        (const float*)d_in[11], (float*)d_out);
}